// Round 2
// baseline (634.343 us; speedup 1.0000x reference)
//
#include <hip/hip_runtime.h>
#include <hip/hip_fp16.h>

typedef _Float16 v8h __attribute__((ext_vector_type(8)));
typedef float v4f __attribute__((ext_vector_type(4)));

__device__ __forceinline__ float2 h2_to_f2(unsigned u) {
    __half2 h = __builtin_bit_cast(__half2, u);
    return __half22float2(h);
}

// ---------------- prep kernels ----------------

// plane_features (384, 64, 64) fp32 -> Pt[3][4096][128] fp16 (channel-last)
__global__ void prep_planes_k(const float* __restrict__ PF, _Float16* __restrict__ Pt) {
    int pl = blockIdx.x >> 7;
    int c  = blockIdx.x & 127;
    const float* src = PF + (size_t)(pl * 128 + c) * 4096;
    _Float16* dst = Pt + (size_t)pl * 4096 * 128 + c;
    for (int pix = threadIdx.x; pix < 4096; pix += 256)
        dst[(size_t)pix * 128] = (_Float16)src[pix];
}

// W (fp32 [K][512], first KB*8 rows) -> Bp fp16 [KB][512][8]; Bp[kb][n][j] = W[kb*8+j][n]
__global__ void prep_w_k(const float* __restrict__ W, _Float16* __restrict__ Bp, int KB) {
    int id = blockIdx.x * 256 + threadIdx.x;
    if (id >= KB * 512) return;
    int kb = id >> 9, n = id & 511;
    v8h v;
#pragma unroll
    for (int j = 0; j < 8; ++j) v[j] = (_Float16)W[(size_t)(kb * 8 + j) * 512 + n];
    *(v8h*)(Bp + (size_t)id * 8) = v;
}

// W1 rows 128..130 (query part) -> W1q fp32 [3][512]
__global__ void prep_w1q_k(const float* __restrict__ W1, float* __restrict__ W1q) {
    int id = blockIdx.x * 256 + threadIdx.x;
    if (id < 3 * 512) W1q[id] = W1[(size_t)(128 + (id >> 9)) * 512 + (id & 511)];
}

// ---------------- fused MLP ----------------
// hbuf swizzle: byte = row*1024 + ((col*2) ^ ((row&7)<<4))

template<int K, bool IS_L1>
__device__ __forceinline__ void do_layer(unsigned short* hbuf,
    const _Float16* __restrict__ Bp, const float* __restrict__ bias,
    const float* __restrict__ W1q, const float* __restrict__ query, int qbase, int t)
{
    const int lane = t & 63;
    const int wv = t >> 6;
    const int wr = wv & 1;        // row half (64 rows)
    const int wc = wv >> 1;       // col group (128 cols)
    const int lc = lane & 15;
    const int lg = lane >> 4;
    const int rowbase = wr * 64;
    const int colbase = wc * 128;

    v4f acc[4][8];
#pragma unroll
    for (int n = 0; n < 8; ++n) {
        float b = bias[colbase + n * 16 + lc];
#pragma unroll
        for (int m = 0; m < 4; ++m) {
#pragma unroll
            for (int j = 0; j < 4; ++j) acc[m][n][j] = b;
        }
    }
    if (IS_L1) {
        // inject raw-query contribution (concat part of h0) at acc init
        float wq0[8], wq1[8], wq2[8];
#pragma unroll
        for (int n = 0; n < 8; ++n) {
            int col = colbase + n * 16 + lc;
            wq0[n] = W1q[col];
            wq1[n] = W1q[512 + col];
            wq2[n] = W1q[1024 + col];
        }
#pragma unroll
        for (int m = 0; m < 4; ++m) {
#pragma unroll
            for (int j = 0; j < 4; ++j) {
                int row = rowbase + m * 16 + lg * 4 + j;
                float a0 = query[(size_t)(qbase + row) * 3 + 0];
                float a1 = query[(size_t)(qbase + row) * 3 + 1];
                float a2 = query[(size_t)(qbase + row) * 3 + 2];
#pragma unroll
                for (int n = 0; n < 8; ++n)
                    acc[m][n][j] += a0 * wq0[n] + a1 * wq1[n] + a2 * wq2[n];
            }
        }
    }

    for (int kb = 0; kb < K / 32; ++kb) {
        v8h a[4];
#pragma unroll
        for (int m = 0; m < 4; ++m) {
            int row = rowbase + m * 16 + lc;               // A row = lane&15
            int off = row * 1024 + (((kb * 32 + 8 * lg) * 2) ^ ((row & 7) << 4));
            a[m] = *(const v8h*)((const char*)hbuf + off);
        }
        const _Float16* bp = Bp + (size_t)(kb * 4 + lg) * 512 * 8;
#pragma unroll
        for (int n = 0; n < 8; ++n) {
            v8h bf = *(const v8h*)(bp + (size_t)(colbase + n * 16 + lc) * 8);
#pragma unroll
            for (int m = 0; m < 4; ++m)
                acc[m][n] = __builtin_amdgcn_mfma_f32_16x16x32_f16(a[m], bf, acc[m][n], 0, 0, 0);
        }
    }
    __syncthreads();   // all reads of hbuf complete
#pragma unroll
    for (int m = 0; m < 4; ++m) {
#pragma unroll
        for (int n = 0; n < 8; ++n) {
#pragma unroll
            for (int j = 0; j < 4; ++j) {
                int row = rowbase + m * 16 + lg * 4 + j;   // C/D: row=(lane>>4)*4+reg
                int col = colbase + n * 16 + lc;           //      col=lane&15
                float v = fmaxf(acc[m][n][j], 0.f);
                _Float16 hv = (_Float16)v;
                int off = row * 1024 + ((col * 2) ^ ((row & 7) << 4));
                *(unsigned short*)((char*)hbuf + off) = __builtin_bit_cast(unsigned short, hv);
            }
        }
    }
    __syncthreads();   // writes visible
}

__global__ __launch_bounds__(512, 2) void mlp_k(
    const _Float16* __restrict__ Pt,
    const float* __restrict__ query,
    const _Float16* __restrict__ W1p, const float* __restrict__ W1q, const float* __restrict__ b1,
    const _Float16* __restrict__ W2p, const float* __restrict__ b2,
    const _Float16* __restrict__ W3p, const float* __restrict__ b3,
    const float* __restrict__ Wo, const float* __restrict__ bo,
    float* __restrict__ out)
{
    __shared__ __align__(16) unsigned short hbuf[128 * 512];   // 128 KiB
    const int t = threadIdx.x;
    const int qbase = blockIdx.x * 128;

    // -------- Phase A: triplane bilinear sampling -> hbuf[:, 0:128] --------
    {
        const int r = t >> 2;       // query row 0..127
        const int p = t & 3;        // channel quarter
        const int n = qbase + r;
        const float q0 = query[(size_t)n * 3 + 0];
        const float q1 = query[(size_t)n * 3 + 1];
        const float q2 = query[(size_t)n * 3 + 2];
        const float inv = 1.0f / 1.1f;
        const float us[3] = { q0 * inv, q1 * inv, q0 * inv };
        const float vs[3] = { q2 * inv, q2 * inv, q1 * inv };
        float facc[32];
#pragma unroll
        for (int i = 0; i < 32; ++i) facc[i] = 0.f;
#pragma unroll
        for (int pl = 0; pl < 3; ++pl) {
            float x = (us[pl] + 1.f) * 31.5f;
            float y = (vs[pl] + 1.f) * 31.5f;
            float xf = floorf(x), yf = floorf(y);
            float wx = x - xf, wy = y - yf;
            int xi = min(max((int)xf, 0), 63);
            int yi = min(max((int)yf, 0), 63);
            int xi1 = min(xi + 1, 63), yi1 = min(yi + 1, 63);
            float w00 = (1.f - wx) * (1.f - wy), w01 = wx * (1.f - wy);
            float w10 = (1.f - wx) * wy,         w11 = wx * wy;
            const _Float16* bse = Pt + (size_t)pl * 4096 * 128 + p * 32;
            const _Float16* p00 = bse + (size_t)(yi  * 64 + xi ) * 128;
            const _Float16* p01 = bse + (size_t)(yi  * 64 + xi1) * 128;
            const _Float16* p10 = bse + (size_t)(yi1 * 64 + xi ) * 128;
            const _Float16* p11 = bse + (size_t)(yi1 * 64 + xi1) * 128;
#pragma unroll
            for (int c = 0; c < 4; ++c) {
                uint4 a00 = *(const uint4*)(p00 + c * 8);
                uint4 a01 = *(const uint4*)(p01 + c * 8);
                uint4 a10 = *(const uint4*)(p10 + c * 8);
                uint4 a11 = *(const uint4*)(p11 + c * 8);
#pragma unroll
                for (int w = 0; w < 4; ++w) {
                    float2 f00 = h2_to_f2(((const unsigned*)&a00)[w]);
                    float2 f01 = h2_to_f2(((const unsigned*)&a01)[w]);
                    float2 f10 = h2_to_f2(((const unsigned*)&a10)[w]);
                    float2 f11 = h2_to_f2(((const unsigned*)&a11)[w]);
                    int o = c * 8 + w * 2;
                    facc[o]     += w00 * f00.x + w01 * f01.x + w10 * f10.x + w11 * f11.x;
                    facc[o + 1] += w00 * f00.y + w01 * f01.y + w10 * f10.y + w11 * f11.y;
                }
            }
        }
#pragma unroll
        for (int c4 = 0; c4 < 4; ++c4) {
            uint4 u;
#pragma unroll
            for (int w = 0; w < 4; ++w) {
                float2 f = make_float2(facc[c4 * 8 + w * 2], facc[c4 * 8 + w * 2 + 1]);
                __half2 h = __float22half2_rn(f);
                ((unsigned*)&u)[w] = __builtin_bit_cast(unsigned, h);
            }
            int col = p * 32 + c4 * 8;
            int off = r * 1024 + ((col * 2) ^ ((r & 7) << 4));
            *(uint4*)((char*)hbuf + off) = u;
        }
    }
    __syncthreads();

    do_layer<128, true >(hbuf, W1p, b1, W1q, query, qbase, t);
    do_layer<512, false>(hbuf, W2p, b2, nullptr, nullptr, 0, t);
    do_layer<512, false>(hbuf, W3p, b3, nullptr, nullptr, 0, t);

    // -------- output layer: out = tanh(h3 . Wo + bo) --------
    {
        const int r = t >> 2;
        const int p = t & 3;
        float sum = 0.f;
#pragma unroll
        for (int c16 = 0; c16 < 16; ++c16) {
            int col = p * 128 + c16 * 8;
            int off = r * 1024 + ((col * 2) ^ ((r & 7) << 4));
            uint4 u = *(const uint4*)((const char*)hbuf + off);
#pragma unroll
            for (int w = 0; w < 4; ++w) {
                float2 f = h2_to_f2(((const unsigned*)&u)[w]);
                sum += f.x * Wo[col + w * 2] + f.y * Wo[col + w * 2 + 1];
            }
        }
        sum += __shfl_xor(sum, 1);
        sum += __shfl_xor(sum, 2);
        if (p == 0) out[qbase + r] = tanhf(sum + bo[0]);
    }
}

// ---------------- launch ----------------
extern "C" void kernel_launch(void* const* d_in, const int* in_sizes, int n_in,
                              void* d_out, int out_size, void* d_ws, size_t ws_size,
                              hipStream_t stream)
{
    (void)in_sizes; (void)n_in; (void)out_size; (void)ws_size;
    const float* PF    = (const float*)d_in[0];
    const float* query = (const float*)d_in[1];
    const float* W1    = (const float*)d_in[2];
    const float* b1    = (const float*)d_in[3];
    const float* W2    = (const float*)d_in[4];
    const float* b2    = (const float*)d_in[5];
    const float* W3    = (const float*)d_in[6];
    const float* b3    = (const float*)d_in[7];
    const float* Wo    = (const float*)d_in[8];
    const float* bo    = (const float*)d_in[9];
    float* out = (float*)d_out;

    char* ws = (char*)d_ws;
    _Float16* Pt  = (_Float16*)(ws);                                   // 3,145,728 B
    _Float16* W1p = (_Float16*)(ws + 3145728);                         //   131,072 B
    _Float16* W2p = (_Float16*)(ws + 3145728 + 131072);                //   524,288 B
    _Float16* W3p = (_Float16*)(ws + 3145728 + 131072 + 524288);       //   524,288 B
    float*    W1q = (float*)  (ws + 3145728 + 131072 + 524288 + 524288); //   6,144 B

    hipLaunchKernelGGL(prep_planes_k, dim3(384), dim3(256), 0, stream, PF, Pt);
    hipLaunchKernelGGL(prep_w_k,      dim3(32),  dim3(256), 0, stream, W1, W1p, 16);
    hipLaunchKernelGGL(prep_w_k,      dim3(128), dim3(256), 0, stream, W2, W2p, 64);
    hipLaunchKernelGGL(prep_w_k,      dim3(128), dim3(256), 0, stream, W3, W3p, 64);
    hipLaunchKernelGGL(prep_w1q_k,    dim3(6),   dim3(256), 0, stream, W1, W1q);
    hipLaunchKernelGGL(mlp_k, dim3(1024), dim3(512), 0, stream,
        Pt, query, W1p, W1q, b1, W2p, b2, W3p, b3, Wo, bo, out);
}

// Round 3
// 625.385 us; speedup vs baseline: 1.0143x; 1.0143x over previous
//
#include <hip/hip_runtime.h>
#include <hip/hip_fp16.h>

typedef _Float16 v8h __attribute__((ext_vector_type(8)));
typedef float v4f __attribute__((ext_vector_type(4)));

__device__ __forceinline__ float2 h2_to_f2(unsigned u) {
    __half2 h = __builtin_bit_cast(__half2, u);
    return __half22float2(h);
}

// ---------------- prep kernels ----------------

// plane_features (384, 64, 64) fp32 -> Pt[3][4096][128] fp16 (channel-last)
// Block = one (plane, y-row): coalesced global read, LDS transpose, 16B/lane write.
__global__ void prep_planes_k(const float* __restrict__ PF, _Float16* __restrict__ Pt) {
    __shared__ _Float16 tile[128][64];   // [c][p], 16 KiB
    const int pl = blockIdx.x >> 6;
    const int y  = blockIdx.x & 63;
    const int t  = threadIdx.x;
    const float* src = PF + (size_t)pl * 128 * 4096 + y * 64;
    // load 128c x 64p: consecutive t -> consecutive p (coalesced)
    for (int it = 0; it < 32; ++it) {
        int idx = it * 256 + t;
        int c = idx >> 6, p = idx & 63;
        tile[c][p] = (_Float16)src[(size_t)c * 4096 + p];
    }
    __syncthreads();
    // store: per (p, 8-chan group) -> uint4; consecutive t -> consecutive 16B (coalesced)
    _Float16* dst = Pt + ((size_t)pl * 4096 + y * 64) * 128;
    for (int it = 0; it < 4; ++it) {
        int idx = it * 256 + t;
        int p = idx >> 4, g = idx & 15;
        uint4 u;
        unsigned short* us = (unsigned short*)&u;
#pragma unroll
        for (int j = 0; j < 8; ++j)
            us[j] = __builtin_bit_cast(unsigned short, tile[g * 8 + j][p]);
        *(uint4*)(dst + (size_t)p * 128 + g * 8) = u;
    }
}

// W (fp32 [K][512], first KB*8 rows) -> Bp fp16 [KB][512][8]; Bp[kb][n][j] = W[kb*8+j][n]
__global__ void prep_w_k(const float* __restrict__ W, _Float16* __restrict__ Bp, int KB) {
    int id = blockIdx.x * 256 + threadIdx.x;
    if (id >= KB * 512) return;
    int kb = id >> 9, n = id & 511;
    v8h v;
#pragma unroll
    for (int j = 0; j < 8; ++j) v[j] = (_Float16)W[(size_t)(kb * 8 + j) * 512 + n];
    *(v8h*)(Bp + (size_t)id * 8) = v;
}

// W1 rows 128..130 (query part) -> W1q fp32 [3][512]
__global__ void prep_w1q_k(const float* __restrict__ W1, float* __restrict__ W1q) {
    int id = blockIdx.x * 256 + threadIdx.x;
    if (id < 3 * 512) W1q[id] = W1[(size_t)(128 + (id >> 9)) * 512 + (id & 511)];
}

// ---------------- fused MLP ----------------
// hbuf swizzle: byte = row*1024 + ((col*2) ^ ((row&7)<<4))

template<int K, bool IS_L1>
__device__ __forceinline__ void do_layer(unsigned short* hbuf,
    const _Float16* __restrict__ Bp, const float* __restrict__ bias,
    const float* __restrict__ W1q, const float* __restrict__ query, int qbase, int t)
{
    const int lane = t & 63;
    const int wv = t >> 6;
    const int wr = wv & 1;        // row half (64 rows)
    const int wc = wv >> 1;       // col group (128 cols)
    const int lc = lane & 15;
    const int lg = lane >> 4;
    const int rowbase = wr * 64;
    const int colbase = wc * 128;

    v4f acc[4][8];
#pragma unroll
    for (int n = 0; n < 8; ++n) {
        float b = bias[colbase + n * 16 + lc];
#pragma unroll
        for (int m = 0; m < 4; ++m) {
#pragma unroll
            for (int j = 0; j < 4; ++j) acc[m][n][j] = b;
        }
    }
    if (IS_L1) {
        // inject raw-query contribution (concat part of h0) at acc init
        float wq0[8], wq1[8], wq2[8];
#pragma unroll
        for (int n = 0; n < 8; ++n) {
            int col = colbase + n * 16 + lc;
            wq0[n] = W1q[col];
            wq1[n] = W1q[512 + col];
            wq2[n] = W1q[1024 + col];
        }
#pragma unroll
        for (int m = 0; m < 4; ++m) {
#pragma unroll
            for (int j = 0; j < 4; ++j) {
                int row = rowbase + m * 16 + lg * 4 + j;
                float a0 = query[(size_t)(qbase + row) * 3 + 0];
                float a1 = query[(size_t)(qbase + row) * 3 + 1];
                float a2 = query[(size_t)(qbase + row) * 3 + 2];
#pragma unroll
                for (int n = 0; n < 8; ++n)
                    acc[m][n][j] += a0 * wq0[n] + a1 * wq1[n] + a2 * wq2[n];
            }
        }
    }

    for (int kb = 0; kb < K / 32; ++kb) {
        v8h a[4];
#pragma unroll
        for (int m = 0; m < 4; ++m) {
            int row = rowbase + m * 16 + lc;               // A row = lane&15
            int off = row * 1024 + (((kb * 32 + 8 * lg) * 2) ^ ((row & 7) << 4));
            a[m] = *(const v8h*)((const char*)hbuf + off);
        }
        const _Float16* bp = Bp + (size_t)(kb * 4 + lg) * 512 * 8;
#pragma unroll
        for (int n = 0; n < 8; ++n) {
            v8h bf = *(const v8h*)(bp + (size_t)(colbase + n * 16 + lc) * 8);
#pragma unroll
            for (int m = 0; m < 4; ++m)
                acc[m][n] = __builtin_amdgcn_mfma_f32_16x16x32_f16(a[m], bf, acc[m][n], 0, 0, 0);
        }
    }
    __syncthreads();   // all reads of hbuf complete
#pragma unroll
    for (int m = 0; m < 4; ++m) {
#pragma unroll
        for (int n = 0; n < 8; ++n) {
#pragma unroll
            for (int j = 0; j < 4; ++j) {
                int row = rowbase + m * 16 + lg * 4 + j;   // C/D: row=(lane>>4)*4+reg
                int col = colbase + n * 16 + lc;           //      col=lane&15
                float v = fmaxf(acc[m][n][j], 0.f);
                _Float16 hv = (_Float16)v;
                int off = row * 1024 + ((col * 2) ^ ((row & 7) << 4));
                *(unsigned short*)((char*)hbuf + off) = __builtin_bit_cast(unsigned short, hv);
            }
        }
    }
    __syncthreads();   // writes visible
}

__global__ __launch_bounds__(512, 1) void mlp_k(
    const _Float16* __restrict__ Pt,
    const float* __restrict__ query,
    const _Float16* __restrict__ W1p, const float* __restrict__ W1q, const float* __restrict__ b1,
    const _Float16* __restrict__ W2p, const float* __restrict__ b2,
    const _Float16* __restrict__ W3p, const float* __restrict__ b3,
    const float* __restrict__ Wo, const float* __restrict__ bo,
    float* __restrict__ out)
{
    __shared__ __align__(16) unsigned short hbuf[128 * 512];   // 128 KiB
    const int t = threadIdx.x;
    const int qbase = blockIdx.x * 128;

    // -------- Phase A: triplane bilinear sampling -> hbuf[:, 0:128] --------
    {
        const int r = t >> 2;       // query row 0..127
        const int p = t & 3;        // channel quarter
        const int n = qbase + r;
        const float q0 = query[(size_t)n * 3 + 0];
        const float q1 = query[(size_t)n * 3 + 1];
        const float q2 = query[(size_t)n * 3 + 2];
        const float inv = 1.0f / 1.1f;
        const float us[3] = { q0 * inv, q1 * inv, q0 * inv };
        const float vs[3] = { q2 * inv, q2 * inv, q1 * inv };
        float facc[32];
#pragma unroll
        for (int i = 0; i < 32; ++i) facc[i] = 0.f;
#pragma unroll
        for (int pl = 0; pl < 3; ++pl) {
            float x = (us[pl] + 1.f) * 31.5f;
            float y = (vs[pl] + 1.f) * 31.5f;
            float xf = floorf(x), yf = floorf(y);
            float wx = x - xf, wy = y - yf;
            int xi = min(max((int)xf, 0), 63);
            int yi = min(max((int)yf, 0), 63);
            int xi1 = min(xi + 1, 63), yi1 = min(yi + 1, 63);
            float w00 = (1.f - wx) * (1.f - wy), w01 = wx * (1.f - wy);
            float w10 = (1.f - wx) * wy,         w11 = wx * wy;
            const _Float16* bse = Pt + (size_t)pl * 4096 * 128 + p * 32;
            const _Float16* p00 = bse + (size_t)(yi  * 64 + xi ) * 128;
            const _Float16* p01 = bse + (size_t)(yi  * 64 + xi1) * 128;
            const _Float16* p10 = bse + (size_t)(yi1 * 64 + xi ) * 128;
            const _Float16* p11 = bse + (size_t)(yi1 * 64 + xi1) * 128;
#pragma unroll
            for (int c = 0; c < 4; ++c) {
                uint4 a00 = *(const uint4*)(p00 + c * 8);
                uint4 a01 = *(const uint4*)(p01 + c * 8);
                uint4 a10 = *(const uint4*)(p10 + c * 8);
                uint4 a11 = *(const uint4*)(p11 + c * 8);
#pragma unroll
                for (int w = 0; w < 4; ++w) {
                    float2 f00 = h2_to_f2(((const unsigned*)&a00)[w]);
                    float2 f01 = h2_to_f2(((const unsigned*)&a01)[w]);
                    float2 f10 = h2_to_f2(((const unsigned*)&a10)[w]);
                    float2 f11 = h2_to_f2(((const unsigned*)&a11)[w]);
                    int o = c * 8 + w * 2;
                    facc[o]     += w00 * f00.x + w01 * f01.x + w10 * f10.x + w11 * f11.x;
                    facc[o + 1] += w00 * f00.y + w01 * f01.y + w10 * f10.y + w11 * f11.y;
                }
            }
        }
#pragma unroll
        for (int c4 = 0; c4 < 4; ++c4) {
            uint4 u;
#pragma unroll
            for (int w = 0; w < 4; ++w) {
                float2 f = make_float2(facc[c4 * 8 + w * 2], facc[c4 * 8 + w * 2 + 1]);
                __half2 h = __float22half2_rn(f);
                ((unsigned*)&u)[w] = __builtin_bit_cast(unsigned, h);
            }
            int col = p * 32 + c4 * 8;
            int off = r * 1024 + ((col * 2) ^ ((r & 7) << 4));
            *(uint4*)((char*)hbuf + off) = u;
        }
    }
    __syncthreads();

    do_layer<128, true >(hbuf, W1p, b1, W1q, query, qbase, t);
    do_layer<512, false>(hbuf, W2p, b2, nullptr, nullptr, 0, t);
    do_layer<512, false>(hbuf, W3p, b3, nullptr, nullptr, 0, t);

    // -------- output layer: out = tanh(h3 . Wo + bo) --------
    {
        const int r = t >> 2;
        const int p = t & 3;
        float sum = 0.f;
#pragma unroll
        for (int c16 = 0; c16 < 16; ++c16) {
            int col = p * 128 + c16 * 8;
            int off = r * 1024 + ((col * 2) ^ ((r & 7) << 4));
            uint4 u = *(const uint4*)((const char*)hbuf + off);
#pragma unroll
            for (int w = 0; w < 4; ++w) {
                float2 f = h2_to_f2(((const unsigned*)&u)[w]);
                sum += f.x * Wo[col + w * 2] + f.y * Wo[col + w * 2 + 1];
            }
        }
        sum += __shfl_xor(sum, 1);
        sum += __shfl_xor(sum, 2);
        if (p == 0) out[qbase + r] = tanhf(sum + bo[0]);
    }
}

// ---------------- launch ----------------
extern "C" void kernel_launch(void* const* d_in, const int* in_sizes, int n_in,
                              void* d_out, int out_size, void* d_ws, size_t ws_size,
                              hipStream_t stream)
{
    (void)in_sizes; (void)n_in; (void)out_size; (void)ws_size;
    const float* PF    = (const float*)d_in[0];
    const float* query = (const float*)d_in[1];
    const float* W1    = (const float*)d_in[2];
    const float* b1    = (const float*)d_in[3];
    const float* W2    = (const float*)d_in[4];
    const float* b2    = (const float*)d_in[5];
    const float* W3    = (const float*)d_in[6];
    const float* b3    = (const float*)d_in[7];
    const float* Wo    = (const float*)d_in[8];
    const float* bo    = (const float*)d_in[9];
    float* out = (float*)d_out;

    char* ws = (char*)d_ws;
    _Float16* Pt  = (_Float16*)(ws);                                   // 3,145,728 B
    _Float16* W1p = (_Float16*)(ws + 3145728);                         //   131,072 B
    _Float16* W2p = (_Float16*)(ws + 3145728 + 131072);                //   524,288 B
    _Float16* W3p = (_Float16*)(ws + 3145728 + 131072 + 524288);       //   524,288 B
    float*    W1q = (float*)  (ws + 3145728 + 131072 + 524288 + 524288); //   6,144 B

    hipLaunchKernelGGL(prep_planes_k, dim3(192), dim3(256), 0, stream, PF, Pt);
    hipLaunchKernelGGL(prep_w_k,      dim3(32),  dim3(256), 0, stream, W1, W1p, 16);
    hipLaunchKernelGGL(prep_w_k,      dim3(128), dim3(256), 0, stream, W2, W2p, 64);
    hipLaunchKernelGGL(prep_w_k,      dim3(128), dim3(256), 0, stream, W3, W3p, 64);
    hipLaunchKernelGGL(prep_w1q_k,    dim3(6),   dim3(256), 0, stream, W1, W1q);
    hipLaunchKernelGGL(mlp_k, dim3(1024), dim3(512), 0, stream,
        Pt, query, W1p, W1q, b1, W2p, b2, W3p, b3, Wo, bo, out);
}

// Round 5
// 612.149 us; speedup vs baseline: 1.0363x; 1.0216x over previous
//
#include <hip/hip_runtime.h>
#include <hip/hip_fp16.h>

typedef _Float16 v8h __attribute__((ext_vector_type(8)));
typedef float v4f __attribute__((ext_vector_type(4)));

__device__ __forceinline__ float2 h2_to_f2(unsigned u) {
    __half2 h = __builtin_bit_cast(__half2, u);
    return __half22float2(h);
}

// ---------------- fused prep kernel ----------------
// blocks 0..191   : plane transpose  (pl = b>>6, y = b&63)
// blocks 192..223 : W1 pack (KB=16)
// blocks 224..351 : W2 pack (KB=64)
// blocks 352..479 : W3 pack (KB=64)
// blocks 480..485 : W1q rows 128..130
__global__ void prep_all_k(const float* __restrict__ PF, _Float16* __restrict__ Pt,
                           const float* __restrict__ W1, _Float16* __restrict__ W1p,
                           float* __restrict__ W1q,
                           const float* __restrict__ W2, _Float16* __restrict__ W2p,
                           const float* __restrict__ W3, _Float16* __restrict__ W3p)
{
    __shared__ _Float16 tile[128][64];   // 16 KiB (plane branch only)
    const int bid = blockIdx.x;
    const int t = threadIdx.x;
    if (bid < 192) {
        const int pl = bid >> 6;
        const int y  = bid & 63;
        const float* src = PF + (size_t)pl * 128 * 4096 + y * 64;
        for (int it = 0; it < 32; ++it) {
            int idx = it * 256 + t;
            int c = idx >> 6, p = idx & 63;
            tile[c][p] = (_Float16)src[(size_t)c * 4096 + p];
        }
        __syncthreads();
        _Float16* dst = Pt + ((size_t)pl * 4096 + y * 64) * 128;
        for (int it = 0; it < 4; ++it) {
            int idx = it * 256 + t;
            int p = idx >> 4, g = idx & 15;
            uint4 u;
            unsigned short* us = (unsigned short*)&u;
#pragma unroll
            for (int j = 0; j < 8; ++j)
                us[j] = __builtin_bit_cast(unsigned short, tile[g * 8 + j][p]);
            *(uint4*)(dst + (size_t)p * 128 + g * 8) = u;
        }
        return;
    }
    const float* W; _Float16* Bp; int id;
    if (bid < 224)      { W = W1; Bp = W1p; id = (bid - 192) * 256 + t; }
    else if (bid < 352) { W = W2; Bp = W2p; id = (bid - 224) * 256 + t; }
    else if (bid < 480) { W = W3; Bp = W3p; id = (bid - 352) * 256 + t; }
    else {
        int qid = (bid - 480) * 256 + t;
        if (qid < 3 * 512) W1q[qid] = W1[(size_t)(128 + (qid >> 9)) * 512 + (qid & 511)];
        return;
    }
    int kb = id >> 9, n = id & 511;
    v8h v;
#pragma unroll
    for (int j = 0; j < 8; ++j) v[j] = (_Float16)W[(size_t)(kb * 8 + j) * 512 + n];
    *(v8h*)(Bp + (size_t)id * 8) = v;
}

// ---------------- fused MLP ----------------
// 256 threads (4 waves), 64 queries/block, hbuf 64 KiB.
// hbuf swizzle: byte = row*1024 + ((col*2) ^ ((row&7)<<4))

template<int K, bool IS_L1>
__device__ __forceinline__ void do_layer(unsigned short* hbuf,
    const _Float16* __restrict__ Bp, const float* __restrict__ bias,
    const float* __restrict__ W1q, const float* __restrict__ query, int qbase, int t)
{
    const int lane = t & 63;
    const int wv = t >> 6;        // wave 0..3 -> col group
    const int lc = lane & 15;
    const int lg = lane >> 4;
    const int colbase = wv * 128;

    v4f acc[4][8];
#pragma unroll
    for (int n = 0; n < 8; ++n) {
        float b = bias[colbase + n * 16 + lc];
#pragma unroll
        for (int m = 0; m < 4; ++m) {
#pragma unroll
            for (int j = 0; j < 4; ++j) acc[m][n][j] = b;
        }
    }
    if (IS_L1) {
        // inject raw-query contribution (concat part of h0) at acc init
        float wq0[8], wq1[8], wq2[8];
#pragma unroll
        for (int n = 0; n < 8; ++n) {
            int col = colbase + n * 16 + lc;
            wq0[n] = W1q[col];
            wq1[n] = W1q[512 + col];
            wq2[n] = W1q[1024 + col];
        }
#pragma unroll
        for (int m = 0; m < 4; ++m) {
#pragma unroll
            for (int j = 0; j < 4; ++j) {
                int row = m * 16 + lg * 4 + j;
                float a0 = query[(size_t)(qbase + row) * 3 + 0];
                float a1 = query[(size_t)(qbase + row) * 3 + 1];
                float a2 = query[(size_t)(qbase + row) * 3 + 2];
#pragma unroll
                for (int n = 0; n < 8; ++n)
                    acc[m][n][j] += a0 * wq0[n] + a1 * wq1[n] + a2 * wq2[n];
            }
        }
    }

    for (int kb = 0; kb < K / 32; ++kb) {
        v8h a[4];
#pragma unroll
        for (int m = 0; m < 4; ++m) {
            int row = m * 16 + lc;                         // A row = lane&15
            int off = row * 1024 + (((kb * 32 + 8 * lg) * 2) ^ ((row & 7) << 4));
            a[m] = *(const v8h*)((const char*)hbuf + off);
        }
        const _Float16* bp = Bp + (size_t)(kb * 4 + lg) * 512 * 8;
#pragma unroll
        for (int n = 0; n < 8; ++n) {
            v8h bf = *(const v8h*)(bp + (size_t)(colbase + n * 16 + lc) * 8);
#pragma unroll
            for (int m = 0; m < 4; ++m)
                acc[m][n] = __builtin_amdgcn_mfma_f32_16x16x32_f16(a[m], bf, acc[m][n], 0, 0, 0);
        }
    }
    __syncthreads();   // all reads of hbuf complete
#pragma unroll
    for (int m = 0; m < 4; ++m) {
#pragma unroll
        for (int n = 0; n < 8; ++n) {
#pragma unroll
            for (int j = 0; j < 4; ++j) {
                int row = m * 16 + lg * 4 + j;             // C/D: row=(lane>>4)*4+reg
                int col = colbase + n * 16 + lc;           //      col=lane&15
                float v = fmaxf(acc[m][n][j], 0.f);
                _Float16 hv = (_Float16)v;
                int off = row * 1024 + ((col * 2) ^ ((row & 7) << 4));
                *(unsigned short*)((char*)hbuf + off) = __builtin_bit_cast(unsigned short, hv);
            }
        }
    }
    __syncthreads();   // writes visible
}

__global__ __launch_bounds__(256, 2) void mlp_k(
    const _Float16* __restrict__ Pt,
    const float* __restrict__ query,
    const _Float16* __restrict__ W1p, const float* __restrict__ W1q, const float* __restrict__ b1,
    const _Float16* __restrict__ W2p, const float* __restrict__ b2,
    const _Float16* __restrict__ W3p, const float* __restrict__ b3,
    const float* __restrict__ Wo, const float* __restrict__ bo,
    float* __restrict__ out)
{
    __shared__ __align__(16) unsigned short hbuf[64 * 512];   // 64 KiB
    const int t = threadIdx.x;
    const int qbase = blockIdx.x * 64;

    // -------- Phase A: triplane bilinear sampling -> hbuf[:, 0:128] --------
    {
        const int r = t >> 2;       // query row 0..63
        const int p = t & 3;        // channel quarter
        const int n = qbase + r;
        const float q0 = query[(size_t)n * 3 + 0];
        const float q1 = query[(size_t)n * 3 + 1];
        const float q2 = query[(size_t)n * 3 + 2];
        const float inv = 1.0f / 1.1f;
        const float us[3] = { q0 * inv, q1 * inv, q0 * inv };
        const float vs[3] = { q2 * inv, q2 * inv, q1 * inv };
        float facc[32];
#pragma unroll
        for (int i = 0; i < 32; ++i) facc[i] = 0.f;
#pragma unroll
        for (int pl = 0; pl < 3; ++pl) {
            float x = (us[pl] + 1.f) * 31.5f;
            float y = (vs[pl] + 1.f) * 31.5f;
            float xf = floorf(x), yf = floorf(y);
            float wx = x - xf, wy = y - yf;
            int xi = min(max((int)xf, 0), 63);
            int yi = min(max((int)yf, 0), 63);
            int xi1 = min(xi + 1, 63), yi1 = min(yi + 1, 63);
            float w00 = (1.f - wx) * (1.f - wy), w01 = wx * (1.f - wy);
            float w10 = (1.f - wx) * wy,         w11 = wx * wy;
            const _Float16* bse = Pt + (size_t)pl * 4096 * 128 + p * 32;
            const _Float16* p00 = bse + (size_t)(yi  * 64 + xi ) * 128;
            const _Float16* p01 = bse + (size_t)(yi  * 64 + xi1) * 128;
            const _Float16* p10 = bse + (size_t)(yi1 * 64 + xi ) * 128;
            const _Float16* p11 = bse + (size_t)(yi1 * 64 + xi1) * 128;
#pragma unroll
            for (int c = 0; c < 4; ++c) {
                uint4 a00 = *(const uint4*)(p00 + c * 8);
                uint4 a01 = *(const uint4*)(p01 + c * 8);
                uint4 a10 = *(const uint4*)(p10 + c * 8);
                uint4 a11 = *(const uint4*)(p11 + c * 8);
#pragma unroll
                for (int w = 0; w < 4; ++w) {
                    float2 f00 = h2_to_f2(((const unsigned*)&a00)[w]);
                    float2 f01 = h2_to_f2(((const unsigned*)&a01)[w]);
                    float2 f10 = h2_to_f2(((const unsigned*)&a10)[w]);
                    float2 f11 = h2_to_f2(((const unsigned*)&a11)[w]);
                    int o = c * 8 + w * 2;
                    facc[o]     += w00 * f00.x + w01 * f01.x + w10 * f10.x + w11 * f11.x;
                    facc[o + 1] += w00 * f00.y + w01 * f01.y + w10 * f10.y + w11 * f11.y;
                }
            }
        }
#pragma unroll
        for (int c4 = 0; c4 < 4; ++c4) {
            uint4 u;
#pragma unroll
            for (int w = 0; w < 4; ++w) {
                float2 f = make_float2(facc[c4 * 8 + w * 2], facc[c4 * 8 + w * 2 + 1]);
                __half2 h = __float22half2_rn(f);
                ((unsigned*)&u)[w] = __builtin_bit_cast(unsigned, h);
            }
            int col = p * 32 + c4 * 8;
            int off = r * 1024 + ((col * 2) ^ ((r & 7) << 4));
            *(uint4*)((char*)hbuf + off) = u;
        }
    }
    __syncthreads();

    do_layer<128, true >(hbuf, W1p, b1, W1q, query, qbase, t);
    do_layer<512, false>(hbuf, W2p, b2, nullptr, nullptr, 0, t);
    do_layer<512, false>(hbuf, W3p, b3, nullptr, nullptr, 0, t);

    // -------- output layer: out = tanh(h3 . Wo + bo) --------
    {
        const int r = t >> 2;
        const int p = t & 3;
        float sum = 0.f;
#pragma unroll
        for (int c16 = 0; c16 < 16; ++c16) {
            int col = p * 128 + c16 * 8;
            int off = r * 1024 + ((col * 2) ^ ((r & 7) << 4));
            uint4 u = *(const uint4*)((const char*)hbuf + off);
#pragma unroll
            for (int w = 0; w < 4; ++w) {
                float2 f = h2_to_f2(((const unsigned*)&u)[w]);
                sum += f.x * Wo[col + w * 2] + f.y * Wo[col + w * 2 + 1];
            }
        }
        sum += __shfl_xor(sum, 1);
        sum += __shfl_xor(sum, 2);
        if (p == 0) out[qbase + r] = tanhf(sum + bo[0]);
    }
}

// ---------------- launch ----------------
extern "C" void kernel_launch(void* const* d_in, const int* in_sizes, int n_in,
                              void* d_out, int out_size, void* d_ws, size_t ws_size,
                              hipStream_t stream)
{
    (void)in_sizes; (void)n_in; (void)out_size; (void)ws_size;
    const float* PF    = (const float*)d_in[0];
    const float* query = (const float*)d_in[1];
    const float* W1    = (const float*)d_in[2];
    const float* b1    = (const float*)d_in[3];
    const float* W2    = (const float*)d_in[4];
    const float* b2    = (const float*)d_in[5];
    const float* W3    = (const float*)d_in[6];
    const float* b3    = (const float*)d_in[7];
    const float* Wo    = (const float*)d_in[8];
    const float* bo    = (const float*)d_in[9];
    float* out = (float*)d_out;

    char* ws = (char*)d_ws;
    _Float16* Pt  = (_Float16*)(ws);                                     // 3,145,728 B
    _Float16* W1p = (_Float16*)(ws + 3145728);                           //   131,072 B
    _Float16* W2p = (_Float16*)(ws + 3145728 + 131072);                  //   524,288 B
    _Float16* W3p = (_Float16*)(ws + 3145728 + 131072 + 524288);         //   524,288 B
    float*    W1q = (float*)  (ws + 3145728 + 131072 + 524288 + 524288); //     6,144 B

    hipLaunchKernelGGL(prep_all_k, dim3(486), dim3(256), 0, stream,
        PF, Pt, W1, W1p, W1q, W2, W2p, W3, W3p);
    hipLaunchKernelGGL(mlp_k, dim3(2048), dim3(256), 0, stream,
        Pt, query, W1p, W1q, b1, W2p, b2, W3p, b3, Wo, bo, out);
}

// Round 10
// 293.477 us; speedup vs baseline: 2.1615x; 2.0859x over previous
//
#include <hip/hip_runtime.h>
#include <hip/hip_fp16.h>

typedef _Float16 v8h __attribute__((ext_vector_type(8)));
typedef float v4f __attribute__((ext_vector_type(4)));

__device__ __forceinline__ float2 h2_to_f2(unsigned u) {
    __half2 h = __builtin_bit_cast(__half2, u);
    return __half22float2(h);
}

// ---------------- fused prep kernel ----------------
// blocks 0..191   : plane transpose  (pl = b>>6, y = b&63)
// blocks 192..223 : W1 pack (KB=16)
// blocks 224..351 : W2 pack (KB=64)
// blocks 352..479 : W3 pack (KB=64)
// blocks 480..485 : W1q rows 128..130
__global__ void prep_all_k(const float* __restrict__ PF, _Float16* __restrict__ Pt,
                           const float* __restrict__ W1, _Float16* __restrict__ W1p,
                           float* __restrict__ W1q,
                           const float* __restrict__ W2, _Float16* __restrict__ W2p,
                           const float* __restrict__ W3, _Float16* __restrict__ W3p)
{
    __shared__ _Float16 tile[128][64];   // 16 KiB (plane branch only)
    const int bid = blockIdx.x;
    const int t = threadIdx.x;
    if (bid < 192) {
        const int pl = bid >> 6;
        const int y  = bid & 63;
        const float* src = PF + (size_t)pl * 128 * 4096 + y * 64;
        for (int it = 0; it < 32; ++it) {
            int idx = it * 256 + t;
            int c = idx >> 6, p = idx & 63;
            tile[c][p] = (_Float16)src[(size_t)c * 4096 + p];
        }
        __syncthreads();
        _Float16* dst = Pt + ((size_t)pl * 4096 + y * 64) * 128;
        for (int it = 0; it < 4; ++it) {
            int idx = it * 256 + t;
            int p = idx >> 4, g = idx & 15;
            uint4 u;
            unsigned short* us = (unsigned short*)&u;
#pragma unroll
            for (int j = 0; j < 8; ++j)
                us[j] = __builtin_bit_cast(unsigned short, tile[g * 8 + j][p]);
            *(uint4*)(dst + (size_t)p * 128 + g * 8) = u;
        }
        return;
    }
    const float* W; _Float16* Bp; int id;
    if (bid < 224)      { W = W1; Bp = W1p; id = (bid - 192) * 256 + t; }
    else if (bid < 352) { W = W2; Bp = W2p; id = (bid - 224) * 256 + t; }
    else if (bid < 480) { W = W3; Bp = W3p; id = (bid - 352) * 256 + t; }
    else {
        int qid = (bid - 480) * 256 + t;
        if (qid < 3 * 512) W1q[qid] = W1[(size_t)(128 + (qid >> 9)) * 512 + (qid & 511)];
        return;
    }
    int kb = id >> 9, n = id & 511;
    v8h v;
#pragma unroll
    for (int j = 0; j < 8; ++j) v[j] = (_Float16)W[(size_t)(kb * 8 + j) * 512 + n];
    *(v8h*)(Bp + (size_t)id * 8) = v;
}

// ---------------- fused MLP ----------------
// 512 threads (8 waves), 64 queries/block, ping-pong hbuf 2x64 KiB (1 block/CU).
// NO in-place LDS overwrite: each layer reads src buffer, writes dst buffer,
// single barrier per phase (barrier guarantees all reads of dst's previous
// role completed before any wave writes it).
// Each wave: all 64 rows x one 64-col group -> acc[4][4] = 64 VGPR.
// swizzle within a buffer: byte = row*1024 + ((col*2) ^ ((row&7)<<4))

template<int K, bool IS_L1>
__device__ __forceinline__ void do_layer(const unsigned short* srcb, unsigned short* dstb,
    const _Float16* __restrict__ Bp, const float* __restrict__ bias,
    const float* __restrict__ W1q, const float* __restrict__ query, int qbase, int t)
{
    const int lane = t & 63;
    const int wv = t >> 6;        // wave 0..7 -> 64-col group
    const int lc = lane & 15;
    const int lg = lane >> 4;
    const int colbase = wv * 64;

    v4f acc[4][4];
#pragma unroll
    for (int n = 0; n < 4; ++n) {
        float b = bias[colbase + n * 16 + lc];
#pragma unroll
        for (int m = 0; m < 4; ++m) {
#pragma unroll
            for (int j = 0; j < 4; ++j) acc[m][n][j] = b;
        }
    }
    if (IS_L1) {
        // inject raw-query contribution (concat part of h0) at acc init
        float wq0[4], wq1[4], wq2[4];
#pragma unroll
        for (int n = 0; n < 4; ++n) {
            int col = colbase + n * 16 + lc;
            wq0[n] = W1q[col];
            wq1[n] = W1q[512 + col];
            wq2[n] = W1q[1024 + col];
        }
#pragma unroll
        for (int m = 0; m < 4; ++m) {
#pragma unroll
            for (int j = 0; j < 4; ++j) {
                int row = m * 16 + lg * 4 + j;
                float a0 = query[(size_t)(qbase + row) * 3 + 0];
                float a1 = query[(size_t)(qbase + row) * 3 + 1];
                float a2 = query[(size_t)(qbase + row) * 3 + 2];
#pragma unroll
                for (int n = 0; n < 4; ++n)
                    acc[m][n][j] += a0 * wq0[n] + a1 * wq1[n] + a2 * wq2[n];
            }
        }
    }

    for (int kb = 0; kb < K / 32; ++kb) {
        v8h a[4];
#pragma unroll
        for (int m = 0; m < 4; ++m) {
            int row = m * 16 + lc;                         // A row = lane&15
            int off = row * 1024 + (((kb * 32 + 8 * lg) * 2) ^ ((row & 7) << 4));
            a[m] = *(const v8h*)((const char*)srcb + off);
        }
        const _Float16* bp = Bp + (size_t)(kb * 4 + lg) * 512 * 8;
#pragma unroll
        for (int n = 0; n < 4; ++n) {
            v8h bf = *(const v8h*)(bp + (size_t)(colbase + n * 16 + lc) * 8);
#pragma unroll
            for (int m = 0; m < 4; ++m)
                acc[m][n] = __builtin_amdgcn_mfma_f32_16x16x32_f16(a[m], bf, acc[m][n], 0, 0, 0);
        }
    }
    // writeback to the OTHER buffer (no WAR hazard with the reads above)
#pragma unroll
    for (int m = 0; m < 4; ++m) {
#pragma unroll
        for (int n = 0; n < 4; ++n) {
#pragma unroll
            for (int j = 0; j < 4; ++j) {
                int row = m * 16 + lg * 4 + j;             // C/D: row=(lane>>4)*4+reg
                int col = colbase + n * 16 + lc;           //      col=lane&15
                float v = fmaxf(acc[m][n][j], 0.f);
                _Float16 hv = (_Float16)v;
                int off = row * 1024 + ((col * 2) ^ ((row & 7) << 4));
                *(unsigned short*)((char*)dstb + off) = __builtin_bit_cast(unsigned short, hv);
            }
        }
    }
    __syncthreads();   // dst writes visible; all src reads complete
}

__global__ void __launch_bounds__(512, 2) mlp_k(
    const _Float16* __restrict__ Pt,
    const float* __restrict__ query,
    const _Float16* __restrict__ W1p, const float* __restrict__ W1q, const float* __restrict__ b1,
    const _Float16* __restrict__ W2p, const float* __restrict__ b2,
    const _Float16* __restrict__ W3p, const float* __restrict__ b3,
    const float* __restrict__ Wo, const float* __restrict__ bo,
    float* __restrict__ out)
{
    __shared__ __align__(16) unsigned short hbuf[2][64 * 512];   // 2 x 64 KiB ping-pong
    const int t = threadIdx.x;
    const int qbase = blockIdx.x * 64;

    // -------- Phase A: triplane bilinear sampling -> hbuf[0][:, 0:128] --------
    {
        const int r = t >> 3;       // query row 0..63
        const int p = t & 7;        // 16-channel group
        const int n = qbase + r;
        const float q0 = query[(size_t)n * 3 + 0];
        const float q1 = query[(size_t)n * 3 + 1];
        const float q2 = query[(size_t)n * 3 + 2];
        const float inv = 1.0f / 1.1f;
        const float us[3] = { q0 * inv, q1 * inv, q0 * inv };
        const float vs[3] = { q2 * inv, q2 * inv, q1 * inv };
        float facc[16];
#pragma unroll
        for (int i = 0; i < 16; ++i) facc[i] = 0.f;
#pragma unroll
        for (int pl = 0; pl < 3; ++pl) {
            float x = (us[pl] + 1.f) * 31.5f;
            float y = (vs[pl] + 1.f) * 31.5f;
            float xf = floorf(x), yf = floorf(y);
            float wx = x - xf, wy = y - yf;
            int xi = min(max((int)xf, 0), 63);
            int yi = min(max((int)yf, 0), 63);
            int xi1 = min(xi + 1, 63), yi1 = min(yi + 1, 63);
            float w00 = (1.f - wx) * (1.f - wy), w01 = wx * (1.f - wy);
            float w10 = (1.f - wx) * wy,         w11 = wx * wy;
            const _Float16* bse = Pt + (size_t)pl * 4096 * 128 + p * 16;
            const _Float16* p00 = bse + (size_t)(yi  * 64 + xi ) * 128;
            const _Float16* p01 = bse + (size_t)(yi  * 64 + xi1) * 128;
            const _Float16* p10 = bse + (size_t)(yi1 * 64 + xi ) * 128;
            const _Float16* p11 = bse + (size_t)(yi1 * 64 + xi1) * 128;
#pragma unroll
            for (int c8 = 0; c8 < 2; ++c8) {
                uint4 a00 = *(const uint4*)(p00 + c8 * 8);
                uint4 a01 = *(const uint4*)(p01 + c8 * 8);
                uint4 a10 = *(const uint4*)(p10 + c8 * 8);
                uint4 a11 = *(const uint4*)(p11 + c8 * 8);
#pragma unroll
                for (int w = 0; w < 4; ++w) {
                    float2 f00 = h2_to_f2(((const unsigned*)&a00)[w]);
                    float2 f01 = h2_to_f2(((const unsigned*)&a01)[w]);
                    float2 f10 = h2_to_f2(((const unsigned*)&a10)[w]);
                    float2 f11 = h2_to_f2(((const unsigned*)&a11)[w]);
                    int o = c8 * 8 + w * 2;
                    facc[o]     += w00 * f00.x + w01 * f01.x + w10 * f10.x + w11 * f11.x;
                    facc[o + 1] += w00 * f00.y + w01 * f01.y + w10 * f10.y + w11 * f11.y;
                }
            }
        }
#pragma unroll
        for (int c8 = 0; c8 < 2; ++c8) {
            uint4 u;
#pragma unroll
            for (int w = 0; w < 4; ++w) {
                float2 f = make_float2(facc[c8 * 8 + w * 2], facc[c8 * 8 + w * 2 + 1]);
                __half2 h = __float22half2_rn(f);
                ((unsigned*)&u)[w] = __builtin_bit_cast(unsigned, h);
            }
            int col = p * 16 + c8 * 8;
            int off = r * 1024 + ((col * 2) ^ ((r & 7) << 4));
            *(uint4*)((char*)hbuf[0] + off) = u;
        }
    }
    __syncthreads();

    do_layer<128, true >(hbuf[0], hbuf[1], W1p, b1, W1q, query, qbase, t);  // buf0 -> buf1
    do_layer<512, false>(hbuf[1], hbuf[0], W2p, b2, nullptr, nullptr, 0, t); // buf1 -> buf0
    do_layer<512, false>(hbuf[0], hbuf[1], W3p, b3, nullptr, nullptr, 0, t); // buf0 -> buf1

    // -------- output layer: out = tanh(h3 . Wo + bo), h3 in hbuf[1] --------
    {
        const int r = t >> 3;
        const int p = t & 7;
        float sum = 0.f;
#pragma unroll
        for (int c8 = 0; c8 < 8; ++c8) {
            int col = p * 64 + c8 * 8;
            int off = r * 1024 + ((col * 2) ^ ((r & 7) << 4));
            uint4 u = *(const uint4*)((const char*)hbuf[1] + off);
#pragma unroll
            for (int w = 0; w < 4; ++w) {
                float2 f = h2_to_f2(((const unsigned*)&u)[w]);
                sum += f.x * Wo[col + w * 2] + f.y * Wo[col + w * 2 + 1];
            }
        }
        sum += __shfl_xor(sum, 1);
        sum += __shfl_xor(sum, 2);
        sum += __shfl_xor(sum, 4);
        if (p == 0) out[qbase + r] = tanhf(sum + bo[0]);
    }
}

// ---------------- launch ----------------
extern "C" void kernel_launch(void* const* d_in, const int* in_sizes, int n_in,
                              void* d_out, int out_size, void* d_ws, size_t ws_size,
                              hipStream_t stream)
{
    (void)in_sizes; (void)n_in; (void)out_size; (void)ws_size;
    const float* PF    = (const float*)d_in[0];
    const float* query = (const float*)d_in[1];
    const float* W1    = (const float*)d_in[2];
    const float* b1    = (const float*)d_in[3];
    const float* W2    = (const float*)d_in[4];
    const float* b2    = (const float*)d_in[5];
    const float* W3    = (const float*)d_in[6];
    const float* b3    = (const float*)d_in[7];
    const float* Wo    = (const float*)d_in[8];
    const float* bo    = (const float*)d_in[9];
    float* out = (float*)d_out;

    char* ws = (char*)d_ws;
    _Float16* Pt  = (_Float16*)(ws);                                     // 3,145,728 B
    _Float16* W1p = (_Float16*)(ws + 3145728);                           //   131,072 B
    _Float16* W2p = (_Float16*)(ws + 3145728 + 131072);                  //   524,288 B
    _Float16* W3p = (_Float16*)(ws + 3145728 + 131072 + 524288);         //   524,288 B
    float*    W1q = (float*)  (ws + 3145728 + 131072 + 524288 + 524288); //     6,144 B

    hipLaunchKernelGGL(prep_all_k, dim3(486), dim3(256), 0, stream,
        PF, Pt, W1, W1p, W1q, W2, W2p, W3, W3p);
    hipLaunchKernelGGL(mlp_k, dim3(2048), dim3(512), 0, stream,
        Pt, query, W1p, W1q, b1, W2p, b2, W3p, b3, Wo, bo, out);
}

// Round 15
// 289.815 us; speedup vs baseline: 2.1888x; 1.0126x over previous
//
#include <hip/hip_runtime.h>
#include <hip/hip_fp16.h>

typedef _Float16 v8h __attribute__((ext_vector_type(8)));
typedef float v4f __attribute__((ext_vector_type(4)));

__device__ __forceinline__ float2 h2_to_f2(unsigned u) {
    __half2 h = __builtin_bit_cast(__half2, u);
    return __half22float2(h);
}

// ---------------- fused prep kernel ----------------
// blocks 0..191   : plane transpose  (pl = b>>6, y = b&63)
// blocks 192..223 : W1 pack (KB=16)
// blocks 224..351 : W2 pack (KB=64)
// blocks 352..479 : W3 pack (KB=64)
// blocks 480..485 : W1q rows 128..130
__global__ void prep_all_k(const float* __restrict__ PF, _Float16* __restrict__ Pt,
                           const float* __restrict__ W1, _Float16* __restrict__ W1p,
                           float* __restrict__ W1q,
                           const float* __restrict__ W2, _Float16* __restrict__ W2p,
                           const float* __restrict__ W3, _Float16* __restrict__ W3p)
{
    __shared__ _Float16 tile[128][64];   // 16 KiB (plane branch only)
    const int bid = blockIdx.x;
    const int t = threadIdx.x;
    if (bid < 192) {
        const int pl = bid >> 6;
        const int y  = bid & 63;
        const float* src = PF + (size_t)pl * 128 * 4096 + y * 64;
        for (int it = 0; it < 32; ++it) {
            int idx = it * 256 + t;
            int c = idx >> 6, p = idx & 63;
            tile[c][p] = (_Float16)src[(size_t)c * 4096 + p];
        }
        __syncthreads();
        _Float16* dst = Pt + ((size_t)pl * 4096 + y * 64) * 128;
        for (int it = 0; it < 4; ++it) {
            int idx = it * 256 + t;
            int p = idx >> 4, g = idx & 15;
            uint4 u;
            unsigned short* us = (unsigned short*)&u;
#pragma unroll
            for (int j = 0; j < 8; ++j)
                us[j] = __builtin_bit_cast(unsigned short, tile[g * 8 + j][p]);
            *(uint4*)(dst + (size_t)p * 128 + g * 8) = u;
        }
        return;
    }
    const float* W; _Float16* Bp; int id;
    if (bid < 224)      { W = W1; Bp = W1p; id = (bid - 192) * 256 + t; }
    else if (bid < 352) { W = W2; Bp = W2p; id = (bid - 224) * 256 + t; }
    else if (bid < 480) { W = W3; Bp = W3p; id = (bid - 352) * 256 + t; }
    else {
        int qid = (bid - 480) * 256 + t;
        if (qid < 3 * 512) W1q[qid] = W1[(size_t)(128 + (qid >> 9)) * 512 + (qid & 511)];
        return;
    }
    int kb = id >> 9, n = id & 511;
    v8h v;
#pragma unroll
    for (int j = 0; j < 8; ++j) v[j] = (_Float16)W[(size_t)(kb * 8 + j) * 512 + n];
    *(v8h*)(Bp + (size_t)id * 8) = v;
}

// ---------------- fused MLP ----------------
// ROUND-10 KNOWN-GOOD GEOMETRY (do not change: 32q/2-block-CU variant failed, quarantined):
// 512 threads (8 waves), 64 queries/block, ping-pong hbuf 2x64 KiB (1 block/CU).
// Each wave: all 64 rows x one 64-col group -> acc[4][4] = 64 VGPR.
// NO in-place LDS overwrite (tripwire-proven WAR hazard): layers ping-pong.
// swizzle within a buffer: byte = row*1024 + ((col*2) ^ ((row&7)<<4))
// NEW vs round 10: 2-deep software pipeline of K-loop (register double-buffer
// of A and B fragments, named even/odd regs). Same addresses, same MFMA order
// (kb,n,m) -> bitwise-identical output; scheduling-only change.

template<int K, bool IS_L1>
__device__ __forceinline__ void do_layer(const unsigned short* srcb, unsigned short* dstb,
    const _Float16* __restrict__ Bp, const float* __restrict__ bias,
    const float* __restrict__ W1q, const float* __restrict__ query, int qbase, int t)
{
    const int lane = t & 63;
    const int wv = t >> 6;        // wave 0..7 -> 64-col group
    const int lc = lane & 15;
    const int lg = lane >> 4;
    const int colbase = wv * 64;

    v4f acc[4][4];
#pragma unroll
    for (int n = 0; n < 4; ++n) {
        float b = bias[colbase + n * 16 + lc];
#pragma unroll
        for (int m = 0; m < 4; ++m) {
#pragma unroll
            for (int j = 0; j < 4; ++j) acc[m][n][j] = b;
        }
    }
    if (IS_L1) {
        // inject raw-query contribution (concat part of h0) at acc init
        float wq0[4], wq1[4], wq2[4];
#pragma unroll
        for (int n = 0; n < 4; ++n) {
            int col = colbase + n * 16 + lc;
            wq0[n] = W1q[col];
            wq1[n] = W1q[512 + col];
            wq2[n] = W1q[1024 + col];
        }
#pragma unroll
        for (int m = 0; m < 4; ++m) {
#pragma unroll
            for (int j = 0; j < 4; ++j) {
                int row = m * 16 + lg * 4 + j;
                float a0 = query[(size_t)(qbase + row) * 3 + 0];
                float a1 = query[(size_t)(qbase + row) * 3 + 1];
                float a2 = query[(size_t)(qbase + row) * 3 + 2];
#pragma unroll
                for (int n = 0; n < 4; ++n)
                    acc[m][n][j] += a0 * wq0[n] + a1 * wq1[n] + a2 * wq2[n];
            }
        }
    }

    constexpr int NKB = K / 32;   // 4 or 16 (even)
    auto loadA = [&](v8h* a, int kb) {
#pragma unroll
        for (int m = 0; m < 4; ++m) {
            int row = m * 16 + lc;                         // A row = lane&15
            int off = row * 1024 + (((kb * 32 + 8 * lg) * 2) ^ ((row & 7) << 4));
            a[m] = *(const v8h*)((const char*)srcb + off);
        }
    };
    auto loadB = [&](v8h* bf, int kb) {
        const _Float16* bp = Bp + (size_t)(kb * 4 + lg) * 512 * 8;
#pragma unroll
        for (int n = 0; n < 4; ++n)
            bf[n] = *(const v8h*)(bp + (size_t)(colbase + n * 16 + lc) * 8);
    };
    auto mfmas = [&](const v8h* a, const v8h* bf) {
#pragma unroll
        for (int n = 0; n < 4; ++n) {
#pragma unroll
            for (int m = 0; m < 4; ++m)
                acc[m][n] = __builtin_amdgcn_mfma_f32_16x16x32_f16(a[m], bf[n], acc[m][n], 0, 0, 0);
        }
    };

    v8h aA[4], bA[4], aB[4], bB[4];
    loadA(aA, 0); loadB(bA, 0);
#pragma unroll
    for (int kb = 0; kb < NKB; kb += 2) {
        loadA(aB, kb + 1); loadB(bB, kb + 1);      // prefetch odd
        mfmas(aA, bA);                             // compute even
        if (kb + 2 < NKB) { loadA(aA, kb + 2); loadB(bA, kb + 2); }  // prefetch next even
        mfmas(aB, bB);                             // compute odd
    }

    // writeback to the OTHER buffer (no WAR hazard with the reads above)
#pragma unroll
    for (int m = 0; m < 4; ++m) {
#pragma unroll
        for (int n = 0; n < 4; ++n) {
#pragma unroll
            for (int j = 0; j < 4; ++j) {
                int row = m * 16 + lg * 4 + j;             // C/D: row=(lane>>4)*4+reg
                int col = colbase + n * 16 + lc;           //      col=lane&15
                float v = fmaxf(acc[m][n][j], 0.f);
                _Float16 hv = (_Float16)v;
                int off = row * 1024 + ((col * 2) ^ ((row & 7) << 4));
                *(unsigned short*)((char*)dstb + off) = __builtin_bit_cast(unsigned short, hv);
            }
        }
    }
    __syncthreads();   // dst writes visible; all src reads complete
}

__global__ void __launch_bounds__(512, 2) mlp_k(
    const _Float16* __restrict__ Pt,
    const float* __restrict__ query,
    const _Float16* __restrict__ W1p, const float* __restrict__ W1q, const float* __restrict__ b1,
    const _Float16* __restrict__ W2p, const float* __restrict__ b2,
    const _Float16* __restrict__ W3p, const float* __restrict__ b3,
    const float* __restrict__ Wo, const float* __restrict__ bo,
    float* __restrict__ out)
{
    __shared__ __align__(16) unsigned short hbuf[2][64 * 512];   // 2 x 64 KiB ping-pong
    const int t = threadIdx.x;
    const int qbase = blockIdx.x * 64;

    // -------- Phase A: triplane bilinear sampling -> hbuf[0][:, 0:128] --------
    {
        const int r = t >> 3;       // query row 0..63
        const int p = t & 7;        // 16-channel group
        const int n = qbase + r;
        const float q0 = query[(size_t)n * 3 + 0];
        const float q1 = query[(size_t)n * 3 + 1];
        const float q2 = query[(size_t)n * 3 + 2];
        const float inv = 1.0f / 1.1f;
        const float us[3] = { q0 * inv, q1 * inv, q0 * inv };
        const float vs[3] = { q2 * inv, q2 * inv, q1 * inv };
        float facc[16];
#pragma unroll
        for (int i = 0; i < 16; ++i) facc[i] = 0.f;
#pragma unroll
        for (int pl = 0; pl < 3; ++pl) {
            float x = (us[pl] + 1.f) * 31.5f;
            float y = (vs[pl] + 1.f) * 31.5f;
            float xf = floorf(x), yf = floorf(y);
            float wx = x - xf, wy = y - yf;
            int xi = min(max((int)xf, 0), 63);
            int yi = min(max((int)yf, 0), 63);
            int xi1 = min(xi + 1, 63), yi1 = min(yi + 1, 63);
            float w00 = (1.f - wx) * (1.f - wy), w01 = wx * (1.f - wy);
            float w10 = (1.f - wx) * wy,         w11 = wx * wy;
            const _Float16* bse = Pt + (size_t)pl * 4096 * 128 + p * 16;
            const _Float16* p00 = bse + (size_t)(yi  * 64 + xi ) * 128;
            const _Float16* p01 = bse + (size_t)(yi  * 64 + xi1) * 128;
            const _Float16* p10 = bse + (size_t)(yi1 * 64 + xi ) * 128;
            const _Float16* p11 = bse + (size_t)(yi1 * 64 + xi1) * 128;
#pragma unroll
            for (int c8 = 0; c8 < 2; ++c8) {
                uint4 a00 = *(const uint4*)(p00 + c8 * 8);
                uint4 a01 = *(const uint4*)(p01 + c8 * 8);
                uint4 a10 = *(const uint4*)(p10 + c8 * 8);
                uint4 a11 = *(const uint4*)(p11 + c8 * 8);
#pragma unroll
                for (int w = 0; w < 4; ++w) {
                    float2 f00 = h2_to_f2(((const unsigned*)&a00)[w]);
                    float2 f01 = h2_to_f2(((const unsigned*)&a01)[w]);
                    float2 f10 = h2_to_f2(((const unsigned*)&a10)[w]);
                    float2 f11 = h2_to_f2(((const unsigned*)&a11)[w]);
                    int o = c8 * 8 + w * 2;
                    facc[o]     += w00 * f00.x + w01 * f01.x + w10 * f10.x + w11 * f11.x;
                    facc[o + 1] += w00 * f00.y + w01 * f01.y + w10 * f10.y + w11 * f11.y;
                }
            }
        }
#pragma unroll
        for (int c8 = 0; c8 < 2; ++c8) {
            uint4 u;
#pragma unroll
            for (int w = 0; w < 4; ++w) {
                float2 f = make_float2(facc[c8 * 8 + w * 2], facc[c8 * 8 + w * 2 + 1]);
                __half2 h = __float22half2_rn(f);
                ((unsigned*)&u)[w] = __builtin_bit_cast(unsigned, h);
            }
            int col = p * 16 + c8 * 8;
            int off = r * 1024 + ((col * 2) ^ ((r & 7) << 4));
            *(uint4*)((char*)hbuf[0] + off) = u;
        }
    }
    __syncthreads();

    do_layer<128, true >(hbuf[0], hbuf[1], W1p, b1, W1q, query, qbase, t);  // buf0 -> buf1
    do_layer<512, false>(hbuf[1], hbuf[0], W2p, b2, nullptr, nullptr, 0, t); // buf1 -> buf0
    do_layer<512, false>(hbuf[0], hbuf[1], W3p, b3, nullptr, nullptr, 0, t); // buf0 -> buf1

    // -------- output layer: out = tanh(h3 . Wo + bo), h3 in hbuf[1] --------
    {
        const int r = t >> 3;
        const int p = t & 7;
        float sum = 0.f;
#pragma unroll
        for (int c8 = 0; c8 < 8; ++c8) {
            int col = p * 64 + c8 * 8;
            int off = r * 1024 + ((col * 2) ^ ((r & 7) << 4));
            uint4 u = *(const uint4*)((const char*)hbuf[1] + off);
#pragma unroll
            for (int w = 0; w < 4; ++w) {
                float2 f = h2_to_f2(((const unsigned*)&u)[w]);
                sum += f.x * Wo[col + w * 2] + f.y * Wo[col + w * 2 + 1];
            }
        }
        sum += __shfl_xor(sum, 1);
        sum += __shfl_xor(sum, 2);
        sum += __shfl_xor(sum, 4);
        if (p == 0) out[qbase + r] = tanhf(sum + bo[0]);
    }
}

// ---------------- launch ----------------
extern "C" void kernel_launch(void* const* d_in, const int* in_sizes, int n_in,
                              void* d_out, int out_size, void* d_ws, size_t ws_size,
                              hipStream_t stream)
{
    (void)in_sizes; (void)n_in; (void)out_size; (void)ws_size;
    const float* PF    = (const float*)d_in[0];
    const float* query = (const float*)d_in[1];
    const float* W1    = (const float*)d_in[2];
    const float* b1    = (const float*)d_in[3];
    const float* W2    = (const float*)d_in[4];
    const float* b2    = (const float*)d_in[5];
    const float* W3    = (const float*)d_in[6];
    const float* b3    = (const float*)d_in[7];
    const float* Wo    = (const float*)d_in[8];
    const float* bo    = (const float*)d_in[9];
    float* out = (float*)d_out;

    char* ws = (char*)d_ws;
    _Float16* Pt  = (_Float16*)(ws);                                     // 3,145,728 B
    _Float16* W1p = (_Float16*)(ws + 3145728);                           //   131,072 B
    _Float16* W2p = (_Float16*)(ws + 3145728 + 131072);                  //   524,288 B
    _Float16* W3p = (_Float16*)(ws + 3145728 + 131072 + 524288);         //   524,288 B
    float*    W1q = (float*)  (ws + 3145728 + 131072 + 524288 + 524288); //     6,144 B

    hipLaunchKernelGGL(prep_all_k, dim3(486), dim3(256), 0, stream,
        PF, Pt, W1, W1p, W1q, W2, W2p, W3, W3p);
    hipLaunchKernelGGL(mlp_k, dim3(2048), dim3(512), 0, stream,
        Pt, query, W1p, W1q, b1, W2p, b2, W3p, b3, Wo, bo, out);
}